// Round 3
// baseline (1115.607 us; speedup 1.0000x reference)
//
#include <hip/hip_runtime.h>

#define SS 1024
#define FF 64
#define HH 64
#define NG 256   // 4H gate columns
#define NT 512   // threads per block (8 waves = 2 per SIMD)
#define KH 32    // K-slice per thread (half of F/H)

__device__ __forceinline__ float sigmoidf_(float x) {
    return __builtin_amdgcn_rcpf(1.0f + __expf(-x));
}
__device__ __forceinline__ float tanhf_(float x) {
    return 1.0f - 2.0f * __builtin_amdgcn_rcpf(__expf(2.0f * x) + 1.0f);
}

// ---- repetition macros (no arrays anywhere -> nothing can be demoted to scratch) ----
#define REP32(M) \
  M(0) M(1) M(2) M(3) M(4) M(5) M(6) M(7) \
  M(8) M(9) M(10) M(11) M(12) M(13) M(14) M(15) \
  M(16) M(17) M(18) M(19) M(20) M(21) M(22) M(23) \
  M(24) M(25) M(26) M(27) M(28) M(29) M(30) M(31)

#define DECL_W(i)  float wx##i, wh##i;
#define LOAD_W(i)  wx##i = wk[(kofs + i) * NG + g]; wh##i = rk[(kofs + i) * NG + g];
#define PIN_W(i)   asm volatile("" : "+v"(wx##i), "+v"(wh##i));
#define DECL_X(i)  float xA##i, xB##i;
#define LOAD_XA(i) xA##i = xb[offA + i];
#define LOAD_XB(i) xB##i = xb[offB + i];

#define FH4(i0,i1,i2,i3) \
  a0 += __int_as_float(__builtin_amdgcn_readlane(hb, kofs + i0)) * wh##i0; \
  a1 += __int_as_float(__builtin_amdgcn_readlane(hb, kofs + i1)) * wh##i1; \
  a2 += __int_as_float(__builtin_amdgcn_readlane(hb, kofs + i2)) * wh##i2; \
  a3 += __int_as_float(__builtin_amdgcn_readlane(hb, kofs + i3)) * wh##i3;

#define FX4(L,i0,i1,i2,i3) \
  a0 += x##L##i0 * wx##i0; \
  a1 += x##L##i1 * wx##i1; \
  a2 += x##L##i2 * wx##i2; \
  a3 += x##L##i3 * wx##i3;

#define FH_ALL  FH4(0,1,2,3)   FH4(4,5,6,7)   FH4(8,9,10,11)  FH4(12,13,14,15) \
                FH4(16,17,18,19) FH4(20,21,22,23) FH4(24,25,26,27) FH4(28,29,30,31)
#define FX_ALL(L) FX4(L,0,1,2,3) FX4(L,4,5,6,7) FX4(L,8,9,10,11) FX4(L,12,13,14,15) \
                  FX4(L,16,17,18,19) FX4(L,20,21,22,23) FX4(L,24,25,26,27) FX4(L,28,29,30,31)

// One full LSTM step. z partials exchanged via double-buffered LDS, ONE barrier
// per step. Every wave redundantly computes h,c per-lane so next step's
// v_readlane broadcasts are wave-local.
#define STEP(t, L) do {                                                        \
    const int bsel = (t) & 1;                                                  \
    float a0 = bg, a1 = 0.0f, a2 = 0.0f, a3 = 0.0f;                            \
    const int hb = __float_as_int(h);                                          \
    FH_ALL                                                                     \
    FX_ALL(L)                                                                  \
    zbuf[bsel][tid] = (a0 + a1) + (a2 + a3);                                   \
    __syncthreads();                                                           \
    const float zi = zbuf[bsel][lane]       + zbuf[bsel][256 + lane];          \
    const float zf = zbuf[bsel][64 + lane]  + zbuf[bsel][320 + lane];          \
    const float zc = zbuf[bsel][128 + lane] + zbuf[bsel][384 + lane];          \
    const float zo = zbuf[bsel][192 + lane] + zbuf[bsel][448 + lane];          \
    const float ig = sigmoidf_(zi);                                            \
    const float fg = sigmoidf_(zf);                                            \
    const float og = sigmoidf_(zo);                                            \
    c = fg * c + ig * tanhf_(zc);                                              \
    h = og * tanhf_(c);                                                        \
    if ((tid >> 6) == 0) {                                                     \
        float r = h * dwl;                                                     \
        r += __shfl_xor(r, 32, 64); r += __shfl_xor(r, 16, 64);                \
        r += __shfl_xor(r, 8, 64);  r += __shfl_xor(r, 4, 64);                 \
        r += __shfl_xor(r, 2, 64);  r += __shfl_xor(r, 1, 64);                 \
        if (lane == 0) outb[t] = sigmoidf_(r + db0);                           \
    }                                                                          \
} while (0)

// One block per batch element (256 blocks = 1/CU). Thread (g = tid&255,
// half = tid>>8) computes k in [half*32,(half+1)*32) partial of gate column g.
// Weights live in named VGPR scalars (asm-pinned, cannot be re-loaded or
// scratch-demoted -- rounds 1/2 lost 1 ms to exactly that). x rows are
// wave-uniform loads (scalar pipe), software-pipelined one step ahead.
__global__ __launch_bounds__(NT, 2)
void lstm_fused(const float* __restrict__ x,
                const float* __restrict__ wk,
                const float* __restrict__ rk,
                const float* __restrict__ bias,
                const float* __restrict__ dw,
                const float* __restrict__ db,
                float* __restrict__ out) {
    const int b    = blockIdx.x;
    const int tid  = threadIdx.x;
    const int lane = tid & 63;
    const int g    = tid & 255;                                        // gate column
    const int kofs = __builtin_amdgcn_readfirstlane((tid >> 8) * KH);  // 0 or 32 (wave-uniform)

    REP32(DECL_W)
    REP32(LOAD_W)
    REP32(PIN_W)

    const float bg  = (kofs == 0) ? bias[g] : 0.0f;  // bias counted once (half 0)
    const float dwl = dw[lane];
    const float db0 = db[0];

    __shared__ float zbuf[2][NT];

    float h = 0.0f, c = 0.0f;
    const float* __restrict__ xb   = x + (size_t)b * SS * FF;
    float* __restrict__       outb = out + (size_t)b * SS;

    REP32(DECL_X)

    // preload x row t=0 into A
    {
        const int offA = __builtin_amdgcn_readfirstlane(kofs);
        REP32(LOAD_XA)
    }

    for (int t = 0; t < SS; t += 2) {
        {   // prefetch row t+1 while computing step t
            const int offB = __builtin_amdgcn_readfirstlane((t + 1) * FF + kofs);
            REP32(LOAD_XB)
        }
        STEP(t, A);
        {   // prefetch row t+2 (clamped) while computing step t+1
            const int t2   = (t + 2 < SS) ? (t + 2) : (SS - 1);
            const int offA = __builtin_amdgcn_readfirstlane(t2 * FF + kofs);
            REP32(LOAD_XA)
        }
        STEP(t + 1, B);
    }
}

extern "C" void kernel_launch(void* const* d_in, const int* in_sizes, int n_in,
                              void* d_out, int out_size, void* d_ws, size_t ws_size,
                              hipStream_t stream) {
    const float* x    = (const float*)d_in[0];
    const float* wk   = (const float*)d_in[1];
    const float* rk   = (const float*)d_in[2];
    const float* bias = (const float*)d_in[3];
    const float* dw   = (const float*)d_in[4];
    const float* db   = (const float*)d_in[5];
    float* out = (float*)d_out;

    hipLaunchKernelGGL(lstm_fused, dim3(256), dim3(NT), 0, stream,
                       x, wk, rk, bias, dw, db, out);
}